// Round 23
// baseline (395.306 us; speedup 1.0000x reference)
//
#include <hip/hip_runtime.h>
#include <cstdint>
#include <cstddef>

#define BB 32
#define AA 8400
#define NBB 32
#define CC 80
#define TOPKN 10
#define NREP 8  // measurement amplification (probe round)

typedef float nfloat4 __attribute__((ext_vector_type(4)));

__device__ __forceinline__ unsigned long long shfl_u64(unsigned long long v,
                                                       int src) {
  const int lo = __shfl((int)(v & 0xffffffffull), src, 64);
  const int hi = __shfl((int)(v >> 32), src, 64);
  return ((unsigned long long)(unsigned int)hi << 32) | (unsigned int)lo;
}

// ===========================================================================
// PROBE ROUND: 4 separate kernels, each repeating its idempotent body NREP
// times (asm-opaque base index per rep blocks LICM) so each gets a top-5
// row with true per-kernel counters. Semantics identical to R21 (absmax 0).
// ===========================================================================

// F: default-fill of the whole output (NT float4 stream).
__global__ __launch_bounds__(256) void fill_default_kernel(
    const int* __restrict__ gt_labels, const float* __restrict__ gt_boxes,
    float* __restrict__ out, int nrep) {
  const int NA = BB * AA;
  const int labels4 = NA / 4;
  const int boxes4_end = labels4 + NA;
  const int total4 = labels4 + NA + NA * 20 + NA / 4;  // 5,779,200
  nfloat4* o4 = reinterpret_cast<nfloat4*>(out);
  for (int rep = 0; rep < nrep; ++rep) {
    int start = blockIdx.x * 256 + threadIdx.x;
    asm volatile("" : "+v"(start));  // opaque
    for (int idx = start; idx < total4; idx += 1024 * 256) {
      nfloat4 v;
      if (idx < labels4) {
        const int fb = (idx * 4) / AA;
        int lab = gt_labels[fb * NBB];
        lab = min(max(lab, 0), 80);
        const float lf = (float)lab;
        v = (nfloat4){lf, lf, lf, lf};
      } else if (idx < boxes4_end) {
        const int aidx = idx - labels4;
        const int fb = aidx / AA;
        v = *reinterpret_cast<const nfloat4*>(gt_boxes + (size_t)fb * NBB * 4);
      } else {
        v = (nfloat4){0.f, 0.f, 0.f, 0.f};
      }
      __builtin_nontemporal_store(v, &o4[idx]);
    }
  }
}

// E: candidate enumeration + register butterfly top-10 (R21 z=0 body).
__global__ __launch_bounds__(64) void enum_topk_kernel(
    const float* __restrict__ pred_scores, const float* __restrict__ pred_boxes,
    const int* __restrict__ gt_labels, const float* __restrict__ gt_boxes,
    const int* __restrict__ gt_mask,
    int* __restrict__ tk, int* __restrict__ posA, int* __restrict__ posI,
    int nrep) {
  const int t = threadIdx.x;
  for (int rep = 0; rep < nrep; ++rep) {
    int g = blockIdx.y * NBB + blockIdx.x;
    asm volatile("" : "+v"(g));  // opaque
    const int b = g / NBB;
    if (t == 0) { posA[g] = 0; posI[g] = 0; }

    const float gx0 = gt_boxes[g * 4 + 0], gy0 = gt_boxes[g * 4 + 1];
    const float gx1 = gt_boxes[g * 4 + 2], gy1 = gt_boxes[g * 4 + 3];
    const int cls = gt_labels[g];
    const bool valid = (gt_mask[g] != 0);
    const float ga1 = (gx1 - gx0) * (gy1 - gy0);

    unsigned long long tkkey[TOPKN];
#pragma unroll
    for (int k = 0; k < TOPKN; k++) tkkey[k] = 0ull;

    if (valid) {
      const int strides[3] = {8, 16, 32};
      const int grids[3] = {80, 40, 20};
      const int offs[3] = {0, 6400, 8000};
      for (int lvl = 0; lvl < 3; lvl++) {
        const float s = (float)strides[lvl];
        const int n = grids[lvl], off = offs[lvl];
        int lx = max(0, (int)floorf(gx0 / s - 0.5f) - 1);
        int hx = min(n - 1, (int)ceilf(gx1 / s - 0.5f) + 1);
        int ly = max(0, (int)floorf(gy0 / s - 0.5f) - 1);
        int hy = min(n - 1, (int)ceilf(gy1 / s - 0.5f) + 1);
        if (hx < lx || hy < ly) continue;
        const int w = hx - lx + 1;
        const int m = w * (hy - ly + 1);
        for (int i = t; i < m; i += 64) {
          const int ix = lx + i % w;
          const int iy = ly + i / w;
          const float apx = ((float)ix + 0.5f) * s;
          const float apy = ((float)iy + 0.5f) * s;
          const float d = fminf(fminf(apx - gx0, apy - gy0),
                                fminf(gx1 - apx, gy1 - apy));
          if (!(d > 1e-8f)) continue;
          const int a = off + iy * n + ix;
          const float* pb = pred_boxes + ((size_t)b * AA + a) * 4;
          const float p0 = pb[0], p1 = pb[1], p2 = pb[2], p3 = pb[3];
          const float iw = fmaxf(fminf(gx1, p2) - fmaxf(gx0, p0), 0.0f);
          const float ih = fmaxf(fminf(gy1, p3) - fmaxf(gy0, p1), 0.0f);
          const float inter = iw * ih;
          const float a2 = (p2 - p0) * (p3 - p1);
          const float iou = fmaxf(inter / (ga1 + a2 - inter + 1e-10f), 0.0f);
          const float sc = pred_scores[((size_t)b * AA + a) * CC + cls];
          const float i2 = iou * iou;
          const float align_v = sc * i2 * i2 * i2;
          const unsigned long long key =
              ((unsigned long long)__float_as_uint(align_v) << 32) |
              (unsigned int)(AA - a);
          if (key > tkkey[TOPKN - 1]) {
            tkkey[TOPKN - 1] = key;
#pragma unroll
            for (int k = TOPKN - 1; k > 0; k--) {
              if (tkkey[k] > tkkey[k - 1]) {
                unsigned long long tmp = tkkey[k];
                tkkey[k] = tkkey[k - 1];
                tkkey[k - 1] = tmp;
              }
            }
          }
        }
      }
    }

#pragma unroll
    for (int s = 1; s < 64; s <<= 1) {
      const int partner = t ^ s;
      unsigned long long other[TOPKN];
#pragma unroll
      for (int k = 0; k < TOPKN; k++) other[k] = shfl_u64(tkkey[k], partner);
      unsigned long long L[TOPKN];
#pragma unroll
      for (int k = 0; k < TOPKN; k++) {
        const unsigned long long o = other[TOPKN - 1 - k];
        L[k] = (tkkey[k] > o) ? tkkey[k] : o;
      }
#pragma unroll
      for (int r = 0; r < TOPKN; r++) {
#pragma unroll
        for (int k = (r & 1); k + 1 < TOPKN; k += 2) {
          if (L[k] < L[k + 1]) {
            const unsigned long long tmp = L[k];
            L[k] = L[k + 1];
            L[k + 1] = tmp;
          }
        }
      }
#pragma unroll
      for (int k = 0; k < TOPKN; k++) tkkey[k] = L[k];
    }

    if (t < TOPKN) {
      const unsigned long long key = tkkey[t];
      tk[g * TOPKN + t] = (key != 0ull) ? (AA - (int)(key & 0xffffffffu)) : -1;
    }
  }
}

// K2: sparse assignment (R16/R21-validated body, rep-looped).
__global__ __launch_bounds__(64) void assign_sparse_kernel(
    const float* __restrict__ pred_scores, const float* __restrict__ pred_boxes,
    const float* __restrict__ anchor_points, const int* __restrict__ gt_labels,
    const float* __restrict__ gt_boxes, const int* __restrict__ gt_mask,
    const int* __restrict__ tk,
    int* __restrict__ resj, float* __restrict__ resAl,
    int* __restrict__ posA, int* __restrict__ posI, int nrep) {
  const int t = threadIdx.x;

  __shared__ float sbox[NBB][4];
  __shared__ int scls[NBB];
  __shared__ int svalid[NBB];
  __shared__ int sa[NBB * TOPKN];

  for (int rep = 0; rep < nrep; ++rep) {
    int j = blockIdx.x;
    asm volatile("" : "+v"(j));  // opaque
    const int b = blockIdx.y;

    if (t < NBB) {
      const int g = b * NBB + t;
      sbox[t][0] = gt_boxes[g * 4 + 0];
      sbox[t][1] = gt_boxes[g * 4 + 1];
      sbox[t][2] = gt_boxes[g * 4 + 2];
      sbox[t][3] = gt_boxes[g * 4 + 3];
      scls[t] = gt_labels[g];
      svalid[t] = (gt_mask[g] != 0) ? 1 : 0;
    }
    for (int e = t; e < NBB * TOPKN; e += 64) sa[e] = tk[b * NBB * TOPKN + e];
    __syncthreads();

    if (t < TOPKN) {
      const int a = sa[j * TOPKN + t];
      if (a >= 0) {
        int cnt = 0;
        for (int q = 0; q < NBB * TOPKN; q++) cnt += (sa[q] == a) ? 1 : 0;

        const float apx = anchor_points[a * 2 + 0];
        const float apy = anchor_points[a * 2 + 1];
        const float* pb = pred_boxes + ((size_t)b * AA + a) * 4;
        const float p0 = pb[0], p1 = pb[1], p2 = pb[2], p3 = pb[3];
        const float a2 = (p2 - p0) * (p3 - p1);

        int jj;
        float iou_f;
        if (cnt == 1) {
          jj = j;
          const float gx0 = sbox[j][0], gy0 = sbox[j][1];
          const float gx1 = sbox[j][2], gy1 = sbox[j][3];
          const float iw = fmaxf(fminf(gx1, p2) - fmaxf(gx0, p0), 0.0f);
          const float ih = fmaxf(fminf(gy1, p3) - fmaxf(gy0, p1), 0.0f);
          const float inter = iw * ih;
          const float a1 = (gx1 - gx0) * (gy1 - gy0);
          iou_f = fmaxf(inter / (a1 + a2 - inter + 1e-10f), 0.0f);
        } else {
          float best_iou = -1.0f;
          int best_j = 0;
          for (int jq = 0; jq < NBB; jq++) {
            const float gx0 = sbox[jq][0], gy0 = sbox[jq][1];
            const float gx1 = sbox[jq][2], gy1 = sbox[jq][3];
            const float d = fminf(fminf(apx - gx0, apy - gy0),
                                  fminf(gx1 - apx, gy1 - apy));
            float iou = 0.0f;
            if (svalid[jq] && d > 1e-8f) {
              const float iw = fmaxf(fminf(gx1, p2) - fmaxf(gx0, p0), 0.0f);
              const float ih = fmaxf(fminf(gy1, p3) - fmaxf(gy0, p1), 0.0f);
              const float inter = iw * ih;
              const float a1 = (gx1 - gx0) * (gy1 - gy0);
              iou = fmaxf(inter / (a1 + a2 - inter + 1e-10f), 0.0f);
            }
            if (iou > best_iou) { best_iou = iou; best_j = jq; }
          }
          jj = best_j;
          iou_f = best_iou;
        }

        const float sc = pred_scores[((size_t)b * AA + a) * CC + scls[jj]];
        const float i2 = iou_f * iou_f;
        const float align_v = sc * i2 * i2 * i2;
        const int e = (b * NBB + j) * TOPKN + t;
        resj[e] = jj;
        resAl[e] = align_v;
        atomicMax(&posA[b * NBB + jj], __float_as_int(align_v));
        atomicMax(&posI[b * NBB + jj], __float_as_int(iou_f));
      }
    }
    __syncthreads();  // WAR on sa/sbox before next rep
  }
}

// K3b: sparse scatter (validated body, rep-looped).
__global__ __launch_bounds__(256) void scatter_out_kernel(
    const int* __restrict__ gt_labels, const float* __restrict__ gt_boxes,
    const int* __restrict__ tk, const int* __restrict__ resj,
    const float* __restrict__ resAl, const int* __restrict__ posA,
    const int* __restrict__ posI, float* __restrict__ out, int nrep) {
  for (int rep = 0; rep < nrep; ++rep) {
    int e = blockIdx.x * 256 + threadIdx.x;
    asm volatile("" : "+v"(e));  // opaque
    if (e >= BB * NBB * TOPKN) continue;
    const int a = tk[e];
    if (a < 0) continue;
    const int b = e / (NBB * TOPKN);
    const int jj = resj[e];
    const float align_v = resAl[e];
    const float pa = __int_as_float(posA[b * NBB + jj]);
    const float pi = __int_as_float(posI[b * NBB + jj]);
    const float norm = align_v * pi / (pa + 1e-8f);
    int label = gt_labels[b * NBB + jj];
    label = min(max(label, 0), 80);
    const size_t aidx = (size_t)b * AA + a;

    out[aidx] = (float)label;
    *reinterpret_cast<float4*>(out + (size_t)BB * AA + aidx * 4) =
        *reinterpret_cast<const float4*>(gt_boxes + ((size_t)b * NBB + jj) * 4);
    if (label < CC)
      out[(size_t)BB * AA * 5 + aidx * CC + label] = norm;
    out[(size_t)BB * AA * 85 + aidx] = 1.0f;
  }
}

// ===========================================================================
extern "C" void kernel_launch(void* const* d_in, const int* in_sizes, int n_in,
                              void* d_out, int out_size, void* d_ws, size_t ws_size,
                              hipStream_t stream) {
  const float* pred_scores = (const float*)d_in[0];
  const float* pred_boxes = (const float*)d_in[1];
  const float* anchor_points = (const float*)d_in[2];
  const int* gt_labels = (const int*)d_in[3];
  const float* gt_boxes = (const float*)d_in[4];
  const int* gt_mask = (const int*)d_in[5];
  float* out = (float*)d_out;
  char* ws = (char*)d_ws;

  const size_t off_tk = 0;
  const size_t off_posA = off_tk + (size_t)BB * NBB * TOPKN * 4;
  const size_t off_posI = off_posA + 4096;
  const size_t off_resj = off_posI + 4096;
  const size_t off_resAl = off_resj + (size_t)BB * NBB * TOPKN * 4;

  int* tk = (int*)(ws + off_tk);
  int* posA = (int*)(ws + off_posA);
  int* posI = (int*)(ws + off_posI);
  int* resj = (int*)(ws + off_resj);
  float* resAl = (float*)(ws + off_resAl);

  fill_default_kernel<<<1024, 256, 0, stream>>>(gt_labels, gt_boxes, out,
                                                NREP);

  dim3 g1(NBB, BB);
  enum_topk_kernel<<<g1, 64, 0, stream>>>(pred_scores, pred_boxes, gt_labels,
                                          gt_boxes, gt_mask, tk, posA, posI,
                                          NREP);

  dim3 g2(NBB, BB);
  assign_sparse_kernel<<<g2, 64, 0, stream>>>(
      pred_scores, pred_boxes, anchor_points, gt_labels, gt_boxes, gt_mask,
      tk, resj, resAl, posA, posI, NREP);

  const int ncand = BB * NBB * TOPKN;
  scatter_out_kernel<<<(ncand + 255) / 256, 256, 0, stream>>>(
      gt_labels, gt_boxes, tk, resj, resAl, posA, posI, out, NREP);
}

// Round 24
// 97.927 us; speedup vs baseline: 4.0367x; 4.0367x over previous
//
#include <hip/hip_runtime.h>
#include <cstdint>
#include <cstddef>

#define BB 32
#define AA 8400
#define NBB 32
#define CC 80
#define TOPKN 10
#define ZSPLIT 4  // sub-blocks per gt (R23 probe: enum was 1-wave/SIMD latency-bound)

typedef float nfloat4 __attribute__((ext_vector_type(4)));

__device__ __forceinline__ unsigned long long shfl_u64(unsigned long long v,
                                                       int src) {
  const int lo = __shfl((int)(v & 0xffffffffull), src, 64);
  const int hi = __shfl((int)(v >> 32), src, 64);
  return ((unsigned long long)(unsigned int)hi << 32) | (unsigned int)lo;
}

// register butterfly top-10 merge across a wave (validated R21): after this,
// every lane holds the descending top-10 of the union of all lanes' lists.
__device__ __forceinline__ void wave_merge10(unsigned long long (&tkkey)[TOPKN]) {
#pragma unroll
  for (int s = 1; s < 64; s <<= 1) {
    const int partner = threadIdx.x ^ s;
    unsigned long long other[TOPKN];
#pragma unroll
    for (int k = 0; k < TOPKN; k++) other[k] = shfl_u64(tkkey[k], partner);
    unsigned long long L[TOPKN];
#pragma unroll
    for (int k = 0; k < TOPKN; k++) {
      const unsigned long long o = other[TOPKN - 1 - k];
      L[k] = (tkkey[k] > o) ? tkkey[k] : o;
    }
#pragma unroll
    for (int r = 0; r < TOPKN; r++) {
#pragma unroll
      for (int k = (r & 1); k + 1 < TOPKN; k += 2) {
        if (L[k] < L[k + 1]) {
          const unsigned long long tmp = L[k];
          L[k] = L[k + 1];
          L[k + 1] = tmp;
        }
      }
    }
#pragma unroll
    for (int k = 0; k < TOPKN; k++) tkkey[k] = L[k];
  }
}

// ===========================================================================
// F: default-fill of the whole output (NT float4 stream), 1024x256.
// Regions (float4 idx, NA=BB*AA): [0,NA/4) labels=clip(gt_labels[b,0]) |
// [NA/4,NA/4+NA) boxes=gt_boxes[b,0] | scores zeros | fg zeros.
// ===========================================================================
__global__ __launch_bounds__(256) void fill_default_kernel(
    const int* __restrict__ gt_labels, const float* __restrict__ gt_boxes,
    float* __restrict__ out) {
  const int NA = BB * AA;
  const int labels4 = NA / 4;
  const int boxes4_end = labels4 + NA;
  const int total4 = labels4 + NA + NA * 20 + NA / 4;  // 5,779,200
  nfloat4* o4 = reinterpret_cast<nfloat4*>(out);
  for (int idx = blockIdx.x * 256 + threadIdx.x; idx < total4;
       idx += 1024 * 256) {
    nfloat4 v;
    if (idx < labels4) {
      const int fb = (idx * 4) / AA;
      int lab = gt_labels[fb * NBB];
      lab = min(max(lab, 0), 80);
      const float lf = (float)lab;
      v = (nfloat4){lf, lf, lf, lf};
    } else if (idx < boxes4_end) {
      const int aidx = idx - labels4;
      const int fb = aidx / AA;
      v = *reinterpret_cast<const nfloat4*>(gt_boxes + (size_t)fb * NBB * 4);
    } else {
      v = (nfloat4){0.f, 0.f, 0.f, 0.f};
    }
    __builtin_nontemporal_store(v, &o4[idx]);
  }
}

// ===========================================================================
// E: partial enumeration. Grid (NBB, BB, ZSPLIT) x 64t. Sub-block z covers
// candidate stripe i = z*64 + t (+256 steps) of the gt's analytic inside-
// rectangle (3-level anchor grid, bit-exact (ix+0.5)*s, exact d>1e-8).
// 4x the waves of R21's enum (16/CU) and ~1/4 the serial gather rounds per
// wave -- attacks the R23-measured latency-bound regime (6.9% occupancy).
// Writes a sorted partial top-10 key list to tkpart[g][z][10].
// key = align_bits<<32 | (8400-a): lax.top_k tie semantics (keys distinct).
// ===========================================================================
__global__ __launch_bounds__(64) void enum_part_kernel(
    const float* __restrict__ pred_scores, const float* __restrict__ pred_boxes,
    const int* __restrict__ gt_labels, const float* __restrict__ gt_boxes,
    const int* __restrict__ gt_mask,
    unsigned long long* __restrict__ tkpart) {
  const int j = blockIdx.x, b = blockIdx.y, z = blockIdx.z, t = threadIdx.x;
  const int g = b * NBB + j;

  const float gx0 = gt_boxes[g * 4 + 0], gy0 = gt_boxes[g * 4 + 1];
  const float gx1 = gt_boxes[g * 4 + 2], gy1 = gt_boxes[g * 4 + 3];
  const int cls = gt_labels[g];
  const bool valid = (gt_mask[g] != 0);
  const float ga1 = (gx1 - gx0) * (gy1 - gy0);

  unsigned long long tkkey[TOPKN];
#pragma unroll
  for (int k = 0; k < TOPKN; k++) tkkey[k] = 0ull;

  if (valid) {
    const int strides[3] = {8, 16, 32};
    const int grids[3] = {80, 40, 20};
    const int offs[3] = {0, 6400, 8000};
    for (int lvl = 0; lvl < 3; lvl++) {
      const float s = (float)strides[lvl];
      const int n = grids[lvl], off = offs[lvl];
      int lx = max(0, (int)floorf(gx0 / s - 0.5f) - 1);
      int hx = min(n - 1, (int)ceilf(gx1 / s - 0.5f) + 1);
      int ly = max(0, (int)floorf(gy0 / s - 0.5f) - 1);
      int hy = min(n - 1, (int)ceilf(gy1 / s - 0.5f) + 1);
      if (hx < lx || hy < ly) continue;
      const int w = hx - lx + 1;
      const int m = w * (hy - ly + 1);
      for (int i = z * 64 + t; i < m; i += ZSPLIT * 64) {
        const int ix = lx + i % w;
        const int iy = ly + i / w;
        const float apx = ((float)ix + 0.5f) * s;
        const float apy = ((float)iy + 0.5f) * s;
        const float d = fminf(fminf(apx - gx0, apy - gy0),
                              fminf(gx1 - apx, gy1 - apy));
        if (!(d > 1e-8f)) continue;
        const int a = off + iy * n + ix;
        const float* pb = pred_boxes + ((size_t)b * AA + a) * 4;
        const float p0 = pb[0], p1 = pb[1], p2 = pb[2], p3 = pb[3];
        const float iw = fmaxf(fminf(gx1, p2) - fmaxf(gx0, p0), 0.0f);
        const float ih = fmaxf(fminf(gy1, p3) - fmaxf(gy0, p1), 0.0f);
        const float inter = iw * ih;
        const float a2 = (p2 - p0) * (p3 - p1);
        const float iou = fmaxf(inter / (ga1 + a2 - inter + 1e-10f), 0.0f);
        const float sc = pred_scores[((size_t)b * AA + a) * CC + cls];
        const float i2 = iou * iou;
        const float align_v = sc * i2 * i2 * i2;
        const unsigned long long key =
            ((unsigned long long)__float_as_uint(align_v) << 32) |
            (unsigned int)(AA - a);
        if (key > tkkey[TOPKN - 1]) {
          tkkey[TOPKN - 1] = key;
#pragma unroll
          for (int k = TOPKN - 1; k > 0; k--) {
            if (tkkey[k] > tkkey[k - 1]) {
              unsigned long long tmp = tkkey[k];
              tkkey[k] = tkkey[k - 1];
              tkkey[k - 1] = tmp;
            }
          }
        }
      }
    }
  }

  wave_merge10(tkkey);

  if (t < TOPKN)
    tkpart[((size_t)g * ZSPLIT + z) * TOPKN + t] = tkkey[t];
}

// ===========================================================================
// M: merge the ZSPLIT partial lists per gt. 1024 blocks x 64t: lane z<ZSPLIT
// loads partial list z (10 u64), others hold zeros; one butterfly merge
// yields the global top-10 (any global winner is in its stripe's top-10).
// Writes tk (anchor indices, -1 pad) and zeroes posA/posI.
// ===========================================================================
__global__ __launch_bounds__(64) void merge_topk_kernel(
    const unsigned long long* __restrict__ tkpart,
    int* __restrict__ tk, int* __restrict__ posA, int* __restrict__ posI) {
  const int g = blockIdx.x, t = threadIdx.x;
  if (t == 0) { posA[g] = 0; posI[g] = 0; }

  unsigned long long tkkey[TOPKN];
#pragma unroll
  for (int k = 0; k < TOPKN; k++) tkkey[k] = 0ull;
  if (t < ZSPLIT) {
#pragma unroll
    for (int k = 0; k < TOPKN; k++)
      tkkey[k] = tkpart[((size_t)g * ZSPLIT + t) * TOPKN + k];
  }

  wave_merge10(tkkey);

  if (t < TOPKN) {
    const unsigned long long key = tkkey[t];
    tk[g * TOPKN + t] = (key != 0ull) ? (AA - (int)(key & 0xffffffffu)) : -1;
  }
}

// ===========================================================================
// K2: sparse assignment (R16/R21-validated). Grid (NBB, BB) x 64t.
// ===========================================================================
__global__ __launch_bounds__(64) void assign_sparse_kernel(
    const float* __restrict__ pred_scores, const float* __restrict__ pred_boxes,
    const float* __restrict__ anchor_points, const int* __restrict__ gt_labels,
    const float* __restrict__ gt_boxes, const int* __restrict__ gt_mask,
    const int* __restrict__ tk,
    int* __restrict__ resj, float* __restrict__ resAl,
    int* __restrict__ posA, int* __restrict__ posI) {
  const int j = blockIdx.x, b = blockIdx.y, t = threadIdx.x;

  __shared__ float sbox[NBB][4];
  __shared__ int scls[NBB];
  __shared__ int svalid[NBB];
  __shared__ int sa[NBB * TOPKN];

  if (t < NBB) {
    const int g = b * NBB + t;
    sbox[t][0] = gt_boxes[g * 4 + 0];
    sbox[t][1] = gt_boxes[g * 4 + 1];
    sbox[t][2] = gt_boxes[g * 4 + 2];
    sbox[t][3] = gt_boxes[g * 4 + 3];
    scls[t] = gt_labels[g];
    svalid[t] = (gt_mask[g] != 0) ? 1 : 0;
  }
  for (int e = t; e < NBB * TOPKN; e += 64) sa[e] = tk[b * NBB * TOPKN + e];
  __syncthreads();

  if (t >= TOPKN) return;
  const int a = sa[j * TOPKN + t];
  if (a < 0) return;

  int cnt = 0;
  for (int q = 0; q < NBB * TOPKN; q++) cnt += (sa[q] == a) ? 1 : 0;

  const float apx = anchor_points[a * 2 + 0];
  const float apy = anchor_points[a * 2 + 1];
  const float* pb = pred_boxes + ((size_t)b * AA + a) * 4;
  const float p0 = pb[0], p1 = pb[1], p2 = pb[2], p3 = pb[3];
  const float a2 = (p2 - p0) * (p3 - p1);

  int jj;
  float iou_f;
  if (cnt == 1) {
    jj = j;
    const float gx0 = sbox[j][0], gy0 = sbox[j][1];
    const float gx1 = sbox[j][2], gy1 = sbox[j][3];
    const float iw = fmaxf(fminf(gx1, p2) - fmaxf(gx0, p0), 0.0f);
    const float ih = fmaxf(fminf(gy1, p3) - fmaxf(gy0, p1), 0.0f);
    const float inter = iw * ih;
    const float a1 = (gx1 - gx0) * (gy1 - gy0);
    iou_f = fmaxf(inter / (a1 + a2 - inter + 1e-10f), 0.0f);
  } else {
    float best_iou = -1.0f;
    int best_j = 0;
    for (int jq = 0; jq < NBB; jq++) {
      const float gx0 = sbox[jq][0], gy0 = sbox[jq][1];
      const float gx1 = sbox[jq][2], gy1 = sbox[jq][3];
      const float d = fminf(fminf(apx - gx0, apy - gy0),
                            fminf(gx1 - apx, gy1 - apy));
      float iou = 0.0f;
      if (svalid[jq] && d > 1e-8f) {
        const float iw = fmaxf(fminf(gx1, p2) - fmaxf(gx0, p0), 0.0f);
        const float ih = fmaxf(fminf(gy1, p3) - fmaxf(gy0, p1), 0.0f);
        const float inter = iw * ih;
        const float a1 = (gx1 - gx0) * (gy1 - gy0);
        iou = fmaxf(inter / (a1 + a2 - inter + 1e-10f), 0.0f);
      }
      if (iou > best_iou) { best_iou = iou; best_j = jq; }  // first-max
    }
    jj = best_j;
    iou_f = best_iou;
  }

  const float sc = pred_scores[((size_t)b * AA + a) * CC + scls[jj]];
  const float i2 = iou_f * iou_f;
  const float align_v = sc * i2 * i2 * i2;
  const int e = (b * NBB + j) * TOPKN + t;
  resj[e] = jj;
  resAl[e] = align_v;
  atomicMax(&posA[b * NBB + jj], __float_as_int(align_v));
  atomicMax(&posI[b * NBB + jj], __float_as_int(iou_f));
}

// ===========================================================================
// K3b: sparse scatter over the defaults (validated). 10240 threads.
// ===========================================================================
__global__ __launch_bounds__(256) void scatter_out_kernel(
    const int* __restrict__ gt_labels, const float* __restrict__ gt_boxes,
    const int* __restrict__ tk, const int* __restrict__ resj,
    const float* __restrict__ resAl, const int* __restrict__ posA,
    const int* __restrict__ posI, float* __restrict__ out) {
  const int e = blockIdx.x * 256 + threadIdx.x;
  if (e >= BB * NBB * TOPKN) return;
  const int a = tk[e];
  if (a < 0) return;
  const int b = e / (NBB * TOPKN);
  const int jj = resj[e];
  const float align_v = resAl[e];
  const float pa = __int_as_float(posA[b * NBB + jj]);
  const float pi = __int_as_float(posI[b * NBB + jj]);
  const float norm = align_v * pi / (pa + 1e-8f);
  int label = gt_labels[b * NBB + jj];
  label = min(max(label, 0), 80);
  const size_t aidx = (size_t)b * AA + a;

  out[aidx] = (float)label;
  *reinterpret_cast<float4*>(out + (size_t)BB * AA + aidx * 4) =
      *reinterpret_cast<const float4*>(gt_boxes + ((size_t)b * NBB + jj) * 4);
  if (label < CC)
    out[(size_t)BB * AA * 5 + aidx * CC + label] = norm;
  out[(size_t)BB * AA * 85 + aidx] = 1.0f;
}

// ===========================================================================
extern "C" void kernel_launch(void* const* d_in, const int* in_sizes, int n_in,
                              void* d_out, int out_size, void* d_ws, size_t ws_size,
                              hipStream_t stream) {
  const float* pred_scores = (const float*)d_in[0];
  const float* pred_boxes = (const float*)d_in[1];
  const float* anchor_points = (const float*)d_in[2];
  const int* gt_labels = (const int*)d_in[3];
  const float* gt_boxes = (const float*)d_in[4];
  const int* gt_mask = (const int*)d_in[5];
  float* out = (float*)d_out;
  char* ws = (char*)d_ws;

  // workspace: tkpart | tk | posA | posI | resj | resAl
  const size_t off_tkpart = 0;  // 1024*ZSPLIT*10*8 = 327,680 B
  const size_t off_tk = off_tkpart + (size_t)BB * NBB * ZSPLIT * TOPKN * 8;
  const size_t off_posA = off_tk + (size_t)BB * NBB * TOPKN * 4;
  const size_t off_posI = off_posA + 4096;
  const size_t off_resj = off_posI + 4096;
  const size_t off_resAl = off_resj + (size_t)BB * NBB * TOPKN * 4;

  unsigned long long* tkpart = (unsigned long long*)(ws + off_tkpart);
  int* tk = (int*)(ws + off_tk);
  int* posA = (int*)(ws + off_posA);
  int* posI = (int*)(ws + off_posI);
  int* resj = (int*)(ws + off_resj);
  float* resAl = (float*)(ws + off_resAl);

  fill_default_kernel<<<1024, 256, 0, stream>>>(gt_labels, gt_boxes, out);

  dim3 gE(NBB, BB, ZSPLIT);
  enum_part_kernel<<<gE, 64, 0, stream>>>(pred_scores, pred_boxes, gt_labels,
                                          gt_boxes, gt_mask, tkpart);

  merge_topk_kernel<<<BB * NBB, 64, 0, stream>>>(tkpart, tk, posA, posI);

  dim3 g2(NBB, BB);
  assign_sparse_kernel<<<g2, 64, 0, stream>>>(
      pred_scores, pred_boxes, anchor_points, gt_labels, gt_boxes, gt_mask,
      tk, resj, resAl, posA, posI);

  const int ncand = BB * NBB * TOPKN;
  scatter_out_kernel<<<(ncand + 255) / 256, 256, 0, stream>>>(
      gt_labels, gt_boxes, tk, resj, resAl, posA, posI, out);
}

// Round 26
// 90.834 us; speedup vs baseline: 4.3520x; 1.0781x over previous
//
#include <hip/hip_runtime.h>
#include <cstdint>
#include <cstddef>

#define BB 32
#define AA 8400
#define NBB 32
#define CC 80
#define TOPKN 10
#define MAXC 1536   // >= max inside-anchors per gt (33^2+17^2+9^2 = 1459)
#define CSTR 16     // cnt padding (ints): 64B per counter
#define ACH 64      // anchors per compact block
#define NCH ((AA + ACH - 1) / ACH)  // 132 chunks per batch

typedef float nfloat4 __attribute__((ext_vector_type(4)));

__device__ __forceinline__ unsigned long long shfl_u64(unsigned long long v,
                                                       int src) {
  const int lo = __shfl((int)(v & 0xffffffffull), src, 64);
  const int hi = __shfl((int)(v >> 32), src, 64);
  return ((unsigned long long)(unsigned int)hi << 32) | (unsigned int)lo;
}

// register butterfly top-10 merge across a wave (validated R21/R23):
// afterwards every lane holds the descending top-10 of the union.
__device__ __forceinline__ void wave_merge10(unsigned long long (&tkkey)[TOPKN]) {
#pragma unroll
  for (int s = 1; s < 64; s <<= 1) {
    const int partner = threadIdx.x ^ s;
    unsigned long long other[TOPKN];
#pragma unroll
    for (int k = 0; k < TOPKN; k++) other[k] = shfl_u64(tkkey[k], partner);
    unsigned long long L[TOPKN];
#pragma unroll
    for (int k = 0; k < TOPKN; k++) {
      const unsigned long long o = other[TOPKN - 1 - k];
      L[k] = (tkkey[k] > o) ? tkkey[k] : o;
    }
#pragma unroll
    for (int r = 0; r < TOPKN; r++) {
#pragma unroll
      for (int k = (r & 1); k + 1 < TOPKN; k += 2) {
        if (L[k] < L[k + 1]) {
          const unsigned long long tmp = L[k];
          L[k] = L[k + 1];
          L[k + 1] = tmp;
        }
      }
    }
#pragma unroll
    for (int k = 0; k < TOPKN; k++) tkkey[k] = L[k];
  }
}

// ===========================================================================
// K0: zero the padded cnt region (1024 counters x 16 ints = 64 KB).
// ===========================================================================
__global__ __launch_bounds__(256) void init_cnt_kernel(int4* __restrict__ cnt4) {
  const int i = blockIdx.x * 256 + threadIdx.x;
  if (i < (BB * NBB * CSTR) / 4) cnt4[i] = make_int4(0, 0, 0, 0);
}

// ===========================================================================
// K1 (fused compact + fill), grid (NCH, BB, 2) x 256t.
//  z=1: fill blocks -- NT float4 stream of the "unassigned" defaults over the
//    92.5 MB output (1/(NCH*BB) slice each). Co-resident with z=0 blocks
//    (R21-validated co-scheduling).
//  z=0: compact blocks -- anchor-major, STREAMING scores (R24 diagnosis:
//    per-gt gathers ran at ~380 GB/s scattered-line; streaming the rows
//    coalesced converts 21 MB scattered into 86 MB streamed, a 3x time win).
//    Block owns 64 anchors of batch b: cooperative 20 KB coalesced load of
//    their score rows into LDS (padded [64][81] -> 2-way bank = free), then
//    wave 0: per anchor x 32 gts inside test (LDS gt cache); hits append
//    key = align_bits<<32 | (8400-a) to cand[g] via ballot/leader atomicAdd
//    (R6-validated wave-agg pattern). List order arbitrary (top10 sorts).
// ===========================================================================
__global__ __launch_bounds__(256) void compact_fill_kernel(
    const float* __restrict__ pred_scores, const float* __restrict__ pred_boxes,
    const float* __restrict__ anchor_points, const int* __restrict__ gt_labels,
    const float* __restrict__ gt_boxes, const int* __restrict__ gt_mask,
    unsigned long long* __restrict__ cand, int* __restrict__ cnt,
    float* __restrict__ out) {
  const int c = blockIdx.x, b = blockIdx.y, t = threadIdx.x;

  if (blockIdx.z == 1) {
    // ---- fill blocks (write-only NT stream) ----
    const int NA = BB * AA;
    const int labels4 = NA / 4;
    const int boxes4_end = labels4 + NA;
    const int total4 = labels4 + NA + NA * 20 + NA / 4;  // 5,779,200
    nfloat4* o4 = reinterpret_cast<nfloat4*>(out);
    const int bid = b * NCH + c;  // 0 .. NCH*BB-1 (4224)
    for (int idx = bid * 256 + t; idx < total4; idx += NCH * BB * 256) {
      nfloat4 v;
      if (idx < labels4) {
        const int fb = (idx * 4) / AA;
        int lab = gt_labels[fb * NBB];
        lab = min(max(lab, 0), 80);
        const float lf = (float)lab;
        v = (nfloat4){lf, lf, lf, lf};
      } else if (idx < boxes4_end) {
        const int aidx = idx - labels4;
        const int fb = aidx / AA;
        v = *reinterpret_cast<const nfloat4*>(gt_boxes + (size_t)fb * NBB * 4);
      } else {
        v = (nfloat4){0.f, 0.f, 0.f, 0.f};
      }
      __builtin_nontemporal_store(v, &o4[idx]);
    }
    return;
  }

  // ---- compact blocks ----
  __shared__ float s_sc[ACH][CC + 1];  // 81-f rows: (17t+cls)%32 distinct
  __shared__ float sbox[NBB][4];
  __shared__ int scls[NBB];
  __shared__ int svalid[NBB];

  const int a0 = c * ACH;
  const int nrows = min(ACH, AA - a0);

  if (t < NBB) {
    const int g = b * NBB + t;
    sbox[t][0] = gt_boxes[g * 4 + 0];
    sbox[t][1] = gt_boxes[g * 4 + 1];
    sbox[t][2] = gt_boxes[g * 4 + 2];
    sbox[t][3] = gt_boxes[g * 4 + 3];
    scls[t] = gt_labels[g];
    svalid[t] = (gt_mask[g] != 0) ? 1 : 0;
  }

  // cooperative coalesced load of nrows score rows (contiguous in memory)
  {
    const float* src = pred_scores + ((size_t)b * AA + a0) * CC;
    const int nf4 = nrows * (CC / 4);  // 20 float4 per row
    for (int i = t; i < nf4; i += 256) {
      const float4 v = reinterpret_cast<const float4*>(src)[i];
      const int fi = i * 4;
      const int row = fi / CC;
      const int col = fi - row * CC;
      s_sc[row][col + 0] = v.x;
      s_sc[row][col + 1] = v.y;
      s_sc[row][col + 2] = v.z;
      s_sc[row][col + 3] = v.w;
    }
  }
  __syncthreads();

  if (t >= 64) return;  // wave 0 processes hits (no further barriers)

  const bool act = (t < nrows);
  const int a = a0 + t;
  float apx = 0.f, apy = 0.f, p0 = 0.f, p1 = 0.f, p2 = 0.f, p3 = 0.f;
  float a2 = 0.f;
  if (act) {
    apx = anchor_points[a * 2 + 0];
    apy = anchor_points[a * 2 + 1];
    const float* pb = pred_boxes + ((size_t)b * AA + a) * 4;
    p0 = pb[0]; p1 = pb[1]; p2 = pb[2]; p3 = pb[3];
    a2 = (p2 - p0) * (p3 - p1);
  }
  const int lane = t;

  for (int j = 0; j < NBB; j++) {
    bool hit = false;
    float align_v = 0.0f;
    if (act && svalid[j]) {
      const float gx0 = sbox[j][0], gy0 = sbox[j][1];
      const float gx1 = sbox[j][2], gy1 = sbox[j][3];
      const float d = fminf(fminf(apx - gx0, apy - gy0),
                            fminf(gx1 - apx, gy1 - apy));
      if (d > 1e-8f) {
        const float iw = fmaxf(fminf(gx1, p2) - fmaxf(gx0, p0), 0.0f);
        const float ih = fmaxf(fminf(gy1, p3) - fmaxf(gy0, p1), 0.0f);
        const float inter = iw * ih;
        const float a1 = (gx1 - gx0) * (gy1 - gy0);
        const float iou = fmaxf(inter / (a1 + a2 - inter + 1e-10f), 0.0f);
        const float s = s_sc[t][scls[j]];
        const float i2 = iou * iou;
        align_v = s * i2 * i2 * i2;
        hit = true;
      }
    }
    const unsigned long long m = __ballot(hit);
    if (m == 0ull) continue;
    const int leader = (int)__ffsll((unsigned long long)m) - 1;
    int base = 0;
    if (lane == leader)
      base = atomicAdd(&cnt[(b * NBB + j) * CSTR], (int)__popcll(m));
    base = __shfl(base, leader);
    if (hit) {
      const int rank = (int)__popcll(m & ((1ull << lane) - 1ull));
      const int pos = base + rank;  // cnt <= 1459 < MAXC: never clips
      const unsigned long long key =
          ((unsigned long long)__float_as_uint(align_v) << 32) |
          (unsigned int)(AA - a);
      cand[(size_t)(b * NBB + j) * MAXC + pos] = key;
    }
  }
}

// ===========================================================================
// K_T: per-gt top-10 of the compacted list. 1024 blocks x 64t: coalesced u64
// strided reads + per-lane insertion + butterfly merge (validated). Writes
// tk (-1 pad) and zeroes posA/posI (before K2's atomics).
// key order: descending u64 == descending align, tie -> smaller anchor idx
// (lax.top_k semantics; keys distinct).
// ===========================================================================
__global__ __launch_bounds__(64) void top10_kernel(
    const unsigned long long* __restrict__ cand, const int* __restrict__ cnt,
    int* __restrict__ tk, int* __restrict__ posA, int* __restrict__ posI) {
  const int g = blockIdx.x, t = threadIdx.x;
  if (t == 0) { posA[g] = 0; posI[g] = 0; }
  const int n = cnt[g * CSTR];

  unsigned long long tkkey[TOPKN];
#pragma unroll
  for (int k = 0; k < TOPKN; k++) tkkey[k] = 0ull;

  for (int i = t; i < n; i += 64) {
    const unsigned long long key = cand[(size_t)g * MAXC + i];
    if (key > tkkey[TOPKN - 1]) {
      tkkey[TOPKN - 1] = key;
#pragma unroll
      for (int k = TOPKN - 1; k > 0; k--) {
        if (tkkey[k] > tkkey[k - 1]) {
          const unsigned long long tmp = tkkey[k];
          tkkey[k] = tkkey[k - 1];
          tkkey[k - 1] = tmp;
        }
      }
    }
  }

  wave_merge10(tkkey);

  if (t < TOPKN) {
    const unsigned long long key = tkkey[t];
    tk[g * TOPKN + t] = (key != 0ull) ? (AA - (int)(key & 0xffffffffu)) : -1;
  }
}

// ===========================================================================
// K2: sparse assignment (R16/R21-validated). Grid (NBB, BB) x 64t.
// ===========================================================================
__global__ __launch_bounds__(64) void assign_sparse_kernel(
    const float* __restrict__ pred_scores, const float* __restrict__ pred_boxes,
    const float* __restrict__ anchor_points, const int* __restrict__ gt_labels,
    const float* __restrict__ gt_boxes, const int* __restrict__ gt_mask,
    const int* __restrict__ tk,
    int* __restrict__ resj, float* __restrict__ resAl,
    int* __restrict__ posA, int* __restrict__ posI) {
  const int j = blockIdx.x, b = blockIdx.y, t = threadIdx.x;

  __shared__ float sbox[NBB][4];
  __shared__ int scls[NBB];
  __shared__ int svalid[NBB];
  __shared__ int sa[NBB * TOPKN];

  if (t < NBB) {
    const int g = b * NBB + t;
    sbox[t][0] = gt_boxes[g * 4 + 0];
    sbox[t][1] = gt_boxes[g * 4 + 1];
    sbox[t][2] = gt_boxes[g * 4 + 2];
    sbox[t][3] = gt_boxes[g * 4 + 3];
    scls[t] = gt_labels[g];
    svalid[t] = (gt_mask[g] != 0) ? 1 : 0;
  }
  for (int e = t; e < NBB * TOPKN; e += 64) sa[e] = tk[b * NBB * TOPKN + e];
  __syncthreads();

  if (t >= TOPKN) return;
  const int a = sa[j * TOPKN + t];
  if (a < 0) return;

  int cnt_l = 0;
  for (int q = 0; q < NBB * TOPKN; q++) cnt_l += (sa[q] == a) ? 1 : 0;

  const float apx = anchor_points[a * 2 + 0];
  const float apy = anchor_points[a * 2 + 1];
  const float* pb = pred_boxes + ((size_t)b * AA + a) * 4;
  const float p0 = pb[0], p1 = pb[1], p2 = pb[2], p3 = pb[3];
  const float a2 = (p2 - p0) * (p3 - p1);

  int jj;
  float iou_f;
  if (cnt_l == 1) {
    jj = j;
    const float gx0 = sbox[j][0], gy0 = sbox[j][1];
    const float gx1 = sbox[j][2], gy1 = sbox[j][3];
    const float iw = fmaxf(fminf(gx1, p2) - fmaxf(gx0, p0), 0.0f);
    const float ih = fmaxf(fminf(gy1, p3) - fmaxf(gy0, p1), 0.0f);
    const float inter = iw * ih;
    const float a1 = (gx1 - gx0) * (gy1 - gy0);
    iou_f = fmaxf(inter / (a1 + a2 - inter + 1e-10f), 0.0f);
  } else {
    float best_iou = -1.0f;
    int best_j = 0;
    for (int jq = 0; jq < NBB; jq++) {
      const float gx0 = sbox[jq][0], gy0 = sbox[jq][1];
      const float gx1 = sbox[jq][2], gy1 = sbox[jq][3];
      const float d = fminf(fminf(apx - gx0, apy - gy0),
                            fminf(gx1 - apx, gy1 - apy));
      float iou = 0.0f;
      if (svalid[jq] && d > 1e-8f) {
        const float iw = fmaxf(fminf(gx1, p2) - fmaxf(gx0, p0), 0.0f);
        const float ih = fmaxf(fminf(gy1, p3) - fmaxf(gy0, p1), 0.0f);
        const float inter = iw * ih;
        const float a1 = (gx1 - gx0) * (gy1 - gy0);
        iou = fmaxf(inter / (a1 + a2 - inter + 1e-10f), 0.0f);
      }
      if (iou > best_iou) { best_iou = iou; best_j = jq; }  // first-max
    }
    jj = best_j;
    iou_f = best_iou;
  }

  const float sc = pred_scores[((size_t)b * AA + a) * CC + scls[jj]];
  const float i2 = iou_f * iou_f;
  const float align_v = sc * i2 * i2 * i2;
  const int e = (b * NBB + j) * TOPKN + t;
  resj[e] = jj;
  resAl[e] = align_v;
  atomicMax(&posA[b * NBB + jj], __float_as_int(align_v));
  atomicMax(&posI[b * NBB + jj], __float_as_int(iou_f));
}

// ===========================================================================
// K3b: sparse scatter over the defaults (validated). 10240 threads.
// ===========================================================================
__global__ __launch_bounds__(256) void scatter_out_kernel(
    const int* __restrict__ gt_labels, const float* __restrict__ gt_boxes,
    const int* __restrict__ tk, const int* __restrict__ resj,
    const float* __restrict__ resAl, const int* __restrict__ posA,
    const int* __restrict__ posI, float* __restrict__ out) {
  const int e = blockIdx.x * 256 + threadIdx.x;
  if (e >= BB * NBB * TOPKN) return;
  const int a = tk[e];
  if (a < 0) return;
  const int b = e / (NBB * TOPKN);
  const int jj = resj[e];
  const float align_v = resAl[e];
  const float pa = __int_as_float(posA[b * NBB + jj]);
  const float pi = __int_as_float(posI[b * NBB + jj]);
  const float norm = align_v * pi / (pa + 1e-8f);
  int label = gt_labels[b * NBB + jj];
  label = min(max(label, 0), 80);
  const size_t aidx = (size_t)b * AA + a;

  out[aidx] = (float)label;
  *reinterpret_cast<float4*>(out + (size_t)BB * AA + aidx * 4) =
      *reinterpret_cast<const float4*>(gt_boxes + ((size_t)b * NBB + jj) * 4);
  if (label < CC)
    out[(size_t)BB * AA * 5 + aidx * CC + label] = norm;
  out[(size_t)BB * AA * 85 + aidx] = 1.0f;
}

// ===========================================================================
extern "C" void kernel_launch(void* const* d_in, const int* in_sizes, int n_in,
                              void* d_out, int out_size, void* d_ws, size_t ws_size,
                              hipStream_t stream) {
  const float* pred_scores = (const float*)d_in[0];
  const float* pred_boxes = (const float*)d_in[1];
  const float* anchor_points = (const float*)d_in[2];
  const int* gt_labels = (const int*)d_in[3];
  const float* gt_boxes = (const float*)d_in[4];
  const int* gt_mask = (const int*)d_in[5];
  float* out = (float*)d_out;
  char* ws = (char*)d_ws;

  // workspace: cand | cnt | tk | posA | posI | resj | resAl (~12.8 MB)
  const size_t off_cand = 0;  // 1024*MAXC*8 = 12.58 MB
  const size_t off_cnt = off_cand + (size_t)BB * NBB * MAXC * 8;
  const size_t off_tk = off_cnt + (size_t)BB * NBB * CSTR * 4;
  const size_t off_posA = off_tk + (size_t)BB * NBB * TOPKN * 4;
  const size_t off_posI = off_posA + 4096;
  const size_t off_resj = off_posI + 4096;
  const size_t off_resAl = off_resj + (size_t)BB * NBB * TOPKN * 4;

  unsigned long long* cand = (unsigned long long*)(ws + off_cand);
  int* cnt = (int*)(ws + off_cnt);
  int* tk = (int*)(ws + off_tk);
  int* posA = (int*)(ws + off_posA);
  int* posI = (int*)(ws + off_posI);
  int* resj = (int*)(ws + off_resj);
  float* resAl = (float*)(ws + off_resAl);

  init_cnt_kernel<<<16, 256, 0, stream>>>((int4*)cnt);

  dim3 gC(NCH, BB, 2);  // z=0: compact, z=1: fill
  compact_fill_kernel<<<gC, 256, 0, stream>>>(
      pred_scores, pred_boxes, anchor_points, gt_labels, gt_boxes, gt_mask,
      cand, cnt, out);

  top10_kernel<<<BB * NBB, 64, 0, stream>>>(cand, cnt, tk, posA, posI);

  dim3 g2(NBB, BB);
  assign_sparse_kernel<<<g2, 64, 0, stream>>>(
      pred_scores, pred_boxes, anchor_points, gt_labels, gt_boxes, gt_mask,
      tk, resj, resAl, posA, posI);

  const int ncand = BB * NBB * TOPKN;
  scatter_out_kernel<<<(ncand + 255) / 256, 256, 0, stream>>>(
      gt_labels, gt_boxes, tk, resj, resAl, posA, posI, out);
}

// Round 27
// 77.951 us; speedup vs baseline: 5.0712x; 1.1653x over previous
//
#include <hip/hip_runtime.h>
#include <cstdint>
#include <cstddef>

#define BB 32
#define AA 8400
#define NBB 32
#define CC 80
#define TOPKN 10
#define MAXC 1536   // >= max inside-anchors per gt (33^2+17^2+9^2 = 1459)
#define CSTR 16     // cnt padding (ints): 64B per counter
#define ACH 64      // anchors per compact block
#define NCH ((AA + ACH - 1) / ACH)  // 132 chunks per batch

typedef float nfloat4 __attribute__((ext_vector_type(4)));

__device__ __forceinline__ unsigned long long shfl_u64(unsigned long long v,
                                                       int src) {
  const int lo = __shfl((int)(v & 0xffffffffull), src, 64);
  const int hi = __shfl((int)(v >> 32), src, 64);
  return ((unsigned long long)(unsigned int)hi << 32) | (unsigned int)lo;
}

// register butterfly top-10 merge across a wave (validated R21/R23):
// afterwards every lane holds the descending top-10 of the union.
__device__ __forceinline__ void wave_merge10(unsigned long long (&tkkey)[TOPKN]) {
#pragma unroll
  for (int s = 1; s < 64; s <<= 1) {
    const int partner = threadIdx.x ^ s;
    unsigned long long other[TOPKN];
#pragma unroll
    for (int k = 0; k < TOPKN; k++) other[k] = shfl_u64(tkkey[k], partner);
    unsigned long long L[TOPKN];
#pragma unroll
    for (int k = 0; k < TOPKN; k++) {
      const unsigned long long o = other[TOPKN - 1 - k];
      L[k] = (tkkey[k] > o) ? tkkey[k] : o;
    }
#pragma unroll
    for (int r = 0; r < TOPKN; r++) {
#pragma unroll
      for (int k = (r & 1); k + 1 < TOPKN; k += 2) {
        if (L[k] < L[k + 1]) {
          const unsigned long long tmp = L[k];
          L[k] = L[k + 1];
          L[k + 1] = tmp;
        }
      }
    }
#pragma unroll
    for (int k = 0; k < TOPKN; k++) tkkey[k] = L[k];
  }
}

// ===========================================================================
// K0: zero the padded cnt region (1024 counters x 16 ints = 64 KB).
// ===========================================================================
__global__ __launch_bounds__(256) void init_cnt_kernel(int4* __restrict__ cnt4) {
  const int i = blockIdx.x * 256 + threadIdx.x;
  if (i < (BB * NBB * CSTR) / 4) cnt4[i] = make_int4(0, 0, 0, 0);
}

// ===========================================================================
// K1 (fused compact + fill), grid (NCH, BB, 2) x 256t.
//  z=1: fill blocks -- NT float4 stream of the "unassigned" defaults.
//  z=0: compact blocks -- anchor-major streaming scores into LDS, then
//    ALL FOUR WAVES compute (R26 fix: wave w handles gts [8w,8w+8) for all
//    64 anchors; R26's wave0-only tail left 3/4 of the block idle and capped
//    the kernel at 2.1 TB/s / 67 us). Per-wave ballot/leader-atomicAdd
//    append (R6-validated); different waves touch different gt counters
//    within a block; list order arbitrary (top10 sorts).
// key = align_bits<<32 | (8400-a): lax.top_k tie semantics (keys distinct).
// ===========================================================================
__global__ __launch_bounds__(256) void compact_fill_kernel(
    const float* __restrict__ pred_scores, const float* __restrict__ pred_boxes,
    const float* __restrict__ anchor_points, const int* __restrict__ gt_labels,
    const float* __restrict__ gt_boxes, const int* __restrict__ gt_mask,
    unsigned long long* __restrict__ cand, int* __restrict__ cnt,
    float* __restrict__ out) {
  const int c = blockIdx.x, b = blockIdx.y, t = threadIdx.x;

  if (blockIdx.z == 1) {
    // ---- fill blocks (write-only NT stream) ----
    const int NA = BB * AA;
    const int labels4 = NA / 4;
    const int boxes4_end = labels4 + NA;
    const int total4 = labels4 + NA + NA * 20 + NA / 4;  // 5,779,200
    nfloat4* o4 = reinterpret_cast<nfloat4*>(out);
    const int bid = b * NCH + c;  // 0 .. NCH*BB-1 (4224)
    for (int idx = bid * 256 + t; idx < total4; idx += NCH * BB * 256) {
      nfloat4 v;
      if (idx < labels4) {
        const int fb = (idx * 4) / AA;
        int lab = gt_labels[fb * NBB];
        lab = min(max(lab, 0), 80);
        const float lf = (float)lab;
        v = (nfloat4){lf, lf, lf, lf};
      } else if (idx < boxes4_end) {
        const int aidx = idx - labels4;
        const int fb = aidx / AA;
        v = *reinterpret_cast<const nfloat4*>(gt_boxes + (size_t)fb * NBB * 4);
      } else {
        v = (nfloat4){0.f, 0.f, 0.f, 0.f};
      }
      __builtin_nontemporal_store(v, &o4[idx]);
    }
    return;
  }

  // ---- compact blocks ----
  __shared__ float s_sc[ACH][CC + 1];  // 81-f rows: stride 324B, 2-way banks
  __shared__ float sbox[NBB][4];
  __shared__ int scls[NBB];
  __shared__ int svalid[NBB];

  const int a0 = c * ACH;
  const int nrows = min(ACH, AA - a0);

  if (t < NBB) {
    const int g = b * NBB + t;
    sbox[t][0] = gt_boxes[g * 4 + 0];
    sbox[t][1] = gt_boxes[g * 4 + 1];
    sbox[t][2] = gt_boxes[g * 4 + 2];
    sbox[t][3] = gt_boxes[g * 4 + 3];
    scls[t] = gt_labels[g];
    svalid[t] = (gt_mask[g] != 0) ? 1 : 0;
  }

  // cooperative coalesced load of nrows score rows (contiguous in memory)
  {
    const float* src = pred_scores + ((size_t)b * AA + a0) * CC;
    const int nf4 = nrows * (CC / 4);  // 20 float4 per row
    for (int i = t; i < nf4; i += 256) {
      const float4 v = reinterpret_cast<const float4*>(src)[i];
      const int fi = i * 4;
      const int row = fi / CC;
      const int col = fi - row * CC;
      s_sc[row][col + 0] = v.x;
      s_sc[row][col + 1] = v.y;
      s_sc[row][col + 2] = v.z;
      s_sc[row][col + 3] = v.w;
    }
  }
  __syncthreads();

  // ALL waves compute: wave w handles gts [8w, 8w+8) over all 64 anchors.
  const int wv = t >> 6;
  const int lane = t & 63;
  const bool act = (lane < nrows);
  const int a = a0 + lane;
  float apx = 0.f, apy = 0.f, p0 = 0.f, p1 = 0.f, p2 = 0.f, p3 = 0.f;
  float a2 = 0.f;
  if (act) {
    apx = anchor_points[a * 2 + 0];
    apy = anchor_points[a * 2 + 1];
    const float* pb = pred_boxes + ((size_t)b * AA + a) * 4;
    p0 = pb[0]; p1 = pb[1]; p2 = pb[2]; p3 = pb[3];
    a2 = (p2 - p0) * (p3 - p1);
  }

  const int j0 = wv * (NBB / 4);
  for (int j = j0; j < j0 + NBB / 4; j++) {
    bool hit = false;
    float align_v = 0.0f;
    if (act && svalid[j]) {
      const float gx0 = sbox[j][0], gy0 = sbox[j][1];
      const float gx1 = sbox[j][2], gy1 = sbox[j][3];
      const float d = fminf(fminf(apx - gx0, apy - gy0),
                            fminf(gx1 - apx, gy1 - apy));
      if (d > 1e-8f) {
        const float iw = fmaxf(fminf(gx1, p2) - fmaxf(gx0, p0), 0.0f);
        const float ih = fmaxf(fminf(gy1, p3) - fmaxf(gy0, p1), 0.0f);
        const float inter = iw * ih;
        const float a1 = (gx1 - gx0) * (gy1 - gy0);
        const float iou = fmaxf(inter / (a1 + a2 - inter + 1e-10f), 0.0f);
        const float s = s_sc[lane][scls[j]];
        const float i2 = iou * iou;
        align_v = s * i2 * i2 * i2;
        hit = true;
      }
    }
    const unsigned long long m = __ballot(hit);
    if (m == 0ull) continue;
    const int leader = (int)__ffsll((unsigned long long)m) - 1;
    int base = 0;
    if (lane == leader)
      base = atomicAdd(&cnt[(b * NBB + j) * CSTR], (int)__popcll(m));
    base = __shfl(base, leader);
    if (hit) {
      const int rank = (int)__popcll(m & ((1ull << lane) - 1ull));
      const int pos = base + rank;  // cnt <= 1459 < MAXC: never clips
      const unsigned long long key =
          ((unsigned long long)__float_as_uint(align_v) << 32) |
          (unsigned int)(AA - a);
      cand[(size_t)(b * NBB + j) * MAXC + pos] = key;
    }
  }
}

// ===========================================================================
// K_T: per-gt top-10 of the compacted list (validated). 1024 x 64t.
// ===========================================================================
__global__ __launch_bounds__(64) void top10_kernel(
    const unsigned long long* __restrict__ cand, const int* __restrict__ cnt,
    int* __restrict__ tk, int* __restrict__ posA, int* __restrict__ posI) {
  const int g = blockIdx.x, t = threadIdx.x;
  if (t == 0) { posA[g] = 0; posI[g] = 0; }
  const int n = cnt[g * CSTR];

  unsigned long long tkkey[TOPKN];
#pragma unroll
  for (int k = 0; k < TOPKN; k++) tkkey[k] = 0ull;

  for (int i = t; i < n; i += 64) {
    const unsigned long long key = cand[(size_t)g * MAXC + i];
    if (key > tkkey[TOPKN - 1]) {
      tkkey[TOPKN - 1] = key;
#pragma unroll
      for (int k = TOPKN - 1; k > 0; k--) {
        if (tkkey[k] > tkkey[k - 1]) {
          const unsigned long long tmp = tkkey[k];
          tkkey[k] = tkkey[k - 1];
          tkkey[k - 1] = tmp;
        }
      }
    }
  }

  wave_merge10(tkkey);

  if (t < TOPKN) {
    const unsigned long long key = tkkey[t];
    tk[g * TOPKN + t] = (key != 0ull) ? (AA - (int)(key & 0xffffffffu)) : -1;
  }
}

// ===========================================================================
// K2: sparse assignment (R16/R21-validated). Grid (NBB, BB) x 64t.
// ===========================================================================
__global__ __launch_bounds__(64) void assign_sparse_kernel(
    const float* __restrict__ pred_scores, const float* __restrict__ pred_boxes,
    const float* __restrict__ anchor_points, const int* __restrict__ gt_labels,
    const float* __restrict__ gt_boxes, const int* __restrict__ gt_mask,
    const int* __restrict__ tk,
    int* __restrict__ resj, float* __restrict__ resAl,
    int* __restrict__ posA, int* __restrict__ posI) {
  const int j = blockIdx.x, b = blockIdx.y, t = threadIdx.x;

  __shared__ float sbox[NBB][4];
  __shared__ int scls[NBB];
  __shared__ int svalid[NBB];
  __shared__ int sa[NBB * TOPKN];

  if (t < NBB) {
    const int g = b * NBB + t;
    sbox[t][0] = gt_boxes[g * 4 + 0];
    sbox[t][1] = gt_boxes[g * 4 + 1];
    sbox[t][2] = gt_boxes[g * 4 + 2];
    sbox[t][3] = gt_boxes[g * 4 + 3];
    scls[t] = gt_labels[g];
    svalid[t] = (gt_mask[g] != 0) ? 1 : 0;
  }
  for (int e = t; e < NBB * TOPKN; e += 64) sa[e] = tk[b * NBB * TOPKN + e];
  __syncthreads();

  if (t >= TOPKN) return;
  const int a = sa[j * TOPKN + t];
  if (a < 0) return;

  int cnt_l = 0;
  for (int q = 0; q < NBB * TOPKN; q++) cnt_l += (sa[q] == a) ? 1 : 0;

  const float apx = anchor_points[a * 2 + 0];
  const float apy = anchor_points[a * 2 + 1];
  const float* pb = pred_boxes + ((size_t)b * AA + a) * 4;
  const float p0 = pb[0], p1 = pb[1], p2 = pb[2], p3 = pb[3];
  const float a2 = (p2 - p0) * (p3 - p1);

  int jj;
  float iou_f;
  if (cnt_l == 1) {
    jj = j;
    const float gx0 = sbox[j][0], gy0 = sbox[j][1];
    const float gx1 = sbox[j][2], gy1 = sbox[j][3];
    const float iw = fmaxf(fminf(gx1, p2) - fmaxf(gx0, p0), 0.0f);
    const float ih = fmaxf(fminf(gy1, p3) - fmaxf(gy0, p1), 0.0f);
    const float inter = iw * ih;
    const float a1 = (gx1 - gx0) * (gy1 - gy0);
    iou_f = fmaxf(inter / (a1 + a2 - inter + 1e-10f), 0.0f);
  } else {
    float best_iou = -1.0f;
    int best_j = 0;
    for (int jq = 0; jq < NBB; jq++) {
      const float gx0 = sbox[jq][0], gy0 = sbox[jq][1];
      const float gx1 = sbox[jq][2], gy1 = sbox[jq][3];
      const float d = fminf(fminf(apx - gx0, apy - gy0),
                            fminf(gx1 - apx, gy1 - apy));
      float iou = 0.0f;
      if (svalid[jq] && d > 1e-8f) {
        const float iw = fmaxf(fminf(gx1, p2) - fmaxf(gx0, p0), 0.0f);
        const float ih = fmaxf(fminf(gy1, p3) - fmaxf(gy0, p1), 0.0f);
        const float inter = iw * ih;
        const float a1 = (gx1 - gx0) * (gy1 - gy0);
        iou = fmaxf(inter / (a1 + a2 - inter + 1e-10f), 0.0f);
      }
      if (iou > best_iou) { best_iou = iou; best_j = jq; }  // first-max
    }
    jj = best_j;
    iou_f = best_iou;
  }

  const float sc = pred_scores[((size_t)b * AA + a) * CC + scls[jj]];
  const float i2 = iou_f * iou_f;
  const float align_v = sc * i2 * i2 * i2;
  const int e = (b * NBB + j) * TOPKN + t;
  resj[e] = jj;
  resAl[e] = align_v;
  atomicMax(&posA[b * NBB + jj], __float_as_int(align_v));
  atomicMax(&posI[b * NBB + jj], __float_as_int(iou_f));
}

// ===========================================================================
// K3b: sparse scatter over the defaults (validated). 10240 threads.
// ===========================================================================
__global__ __launch_bounds__(256) void scatter_out_kernel(
    const int* __restrict__ gt_labels, const float* __restrict__ gt_boxes,
    const int* __restrict__ tk, const int* __restrict__ resj,
    const float* __restrict__ resAl, const int* __restrict__ posA,
    const int* __restrict__ posI, float* __restrict__ out) {
  const int e = blockIdx.x * 256 + threadIdx.x;
  if (e >= BB * NBB * TOPKN) return;
  const int a = tk[e];
  if (a < 0) return;
  const int b = e / (NBB * TOPKN);
  const int jj = resj[e];
  const float align_v = resAl[e];
  const float pa = __int_as_float(posA[b * NBB + jj]);
  const float pi = __int_as_float(posI[b * NBB + jj]);
  const float norm = align_v * pi / (pa + 1e-8f);
  int label = gt_labels[b * NBB + jj];
  label = min(max(label, 0), 80);
  const size_t aidx = (size_t)b * AA + a;

  out[aidx] = (float)label;
  *reinterpret_cast<float4*>(out + (size_t)BB * AA + aidx * 4) =
      *reinterpret_cast<const float4*>(gt_boxes + ((size_t)b * NBB + jj) * 4);
  if (label < CC)
    out[(size_t)BB * AA * 5 + aidx * CC + label] = norm;
  out[(size_t)BB * AA * 85 + aidx] = 1.0f;
}

// ===========================================================================
extern "C" void kernel_launch(void* const* d_in, const int* in_sizes, int n_in,
                              void* d_out, int out_size, void* d_ws, size_t ws_size,
                              hipStream_t stream) {
  const float* pred_scores = (const float*)d_in[0];
  const float* pred_boxes = (const float*)d_in[1];
  const float* anchor_points = (const float*)d_in[2];
  const int* gt_labels = (const int*)d_in[3];
  const float* gt_boxes = (const float*)d_in[4];
  const int* gt_mask = (const int*)d_in[5];
  float* out = (float*)d_out;
  char* ws = (char*)d_ws;

  // workspace: cand | cnt | tk | posA | posI | resj | resAl (~12.8 MB)
  const size_t off_cand = 0;  // 1024*MAXC*8 = 12.58 MB
  const size_t off_cnt = off_cand + (size_t)BB * NBB * MAXC * 8;
  const size_t off_tk = off_cnt + (size_t)BB * NBB * CSTR * 4;
  const size_t off_posA = off_tk + (size_t)BB * NBB * TOPKN * 4;
  const size_t off_posI = off_posA + 4096;
  const size_t off_resj = off_posI + 4096;
  const size_t off_resAl = off_resj + (size_t)BB * NBB * TOPKN * 4;

  unsigned long long* cand = (unsigned long long*)(ws + off_cand);
  int* cnt = (int*)(ws + off_cnt);
  int* tk = (int*)(ws + off_tk);
  int* posA = (int*)(ws + off_posA);
  int* posI = (int*)(ws + off_posI);
  int* resj = (int*)(ws + off_resj);
  float* resAl = (float*)(ws + off_resAl);

  init_cnt_kernel<<<16, 256, 0, stream>>>((int4*)cnt);

  dim3 gC(NCH, BB, 2);  // z=0: compact (all waves compute), z=1: fill
  compact_fill_kernel<<<gC, 256, 0, stream>>>(
      pred_scores, pred_boxes, anchor_points, gt_labels, gt_boxes, gt_mask,
      cand, cnt, out);

  top10_kernel<<<BB * NBB, 64, 0, stream>>>(cand, cnt, tk, posA, posI);

  dim3 g2(NBB, BB);
  assign_sparse_kernel<<<g2, 64, 0, stream>>>(
      pred_scores, pred_boxes, anchor_points, gt_labels, gt_boxes, gt_mask,
      tk, resj, resAl, posA, posI);

  const int ncand = BB * NBB * TOPKN;
  scatter_out_kernel<<<(ncand + 255) / 256, 256, 0, stream>>>(
      gt_labels, gt_boxes, tk, resj, resAl, posA, posI, out);
}

// Round 30
// 46.738 us; speedup vs baseline: 8.4579x; 1.6678x over previous
//
#include <hip/hip_runtime.h>
#include <cstdint>
#include <cstddef>

#define BB 32
#define AA 8400
#define NBB 32
#define CC 80
#define TOPKN 10

// native clang vector for __builtin_nontemporal_store (HIP float4 is a
// class type the builtin rejects; this alias is layout-identical)
typedef float nfloat4 __attribute__((ext_vector_type(4)));

// ===========================================================================
// K1 (block-specialized): grid (NBB, BB, 2) x 256t.  [R20-best: 47.4 us]
//  z=1 blocks: ONLY stream the "unassigned" default output (1/1024 slice of
//    92.5 MB, NT float4 stores). Store-bound.
//  z=0 blocks: ONLY candidate enumeration + top-10 for gt (j,b). Latency-
//    bound gathers. Co-residency of the two block types overlaps the store
//    stream with gather latency at the CU scheduler level (m114 mechanism).
// Fill regions (float4 idx, NA=BB*AA): [0,NA/4) labels=clip(gt_labels[b,0])
// | [NA/4,NA/4+NA) boxes=gt_boxes[b,0] | scores zeros | fg zeros.
// Enum: 3-level anchor grid (bit-exact (ix+0.5)*s), exact d>1e-8 re-test,
// block top-10 via padded LDS merge ([256][11] u64, stride 88B -> 2-way
// bank aliasing = free). key = align_bits<<32 | (8400-a): lax.top_k ties.
// ===========================================================================
__global__ __launch_bounds__(256) void gt_topk_kernel(
    const float* __restrict__ pred_scores, const float* __restrict__ pred_boxes,
    const int* __restrict__ gt_labels, const float* __restrict__ gt_boxes,
    const int* __restrict__ gt_mask,
    int* __restrict__ tk, int* __restrict__ posA, int* __restrict__ posI,
    float* __restrict__ out) {
  const int j = blockIdx.x, b = blockIdx.y, t = threadIdx.x;
  const int g = b * NBB + j;

  if (blockIdx.z == 1) {
    // ---- fill-only blocks (write-only NT stream) ----
    const int NA = BB * AA;
    const int labels4 = NA / 4;
    const int boxes4_end = labels4 + NA;
    const int total4 = labels4 + NA + NA * 20 + NA / 4;  // 5,779,200
    nfloat4* o4 = reinterpret_cast<nfloat4*>(out);
    for (int idx = (g << 8) + t; idx < total4; idx += 1024 * 256) {
      nfloat4 v;
      if (idx < labels4) {
        const int fb = (idx * 4) / AA;
        int lab = gt_labels[fb * NBB];
        lab = min(max(lab, 0), 80);
        const float lf = (float)lab;
        v = (nfloat4){lf, lf, lf, lf};
      } else if (idx < boxes4_end) {
        const int aidx = idx - labels4;
        const int fb = aidx / AA;
        v = *reinterpret_cast<const nfloat4*>(gt_boxes + (size_t)fb * NBB * 4);
      } else {
        v = (nfloat4){0.f, 0.f, 0.f, 0.f};
      }
      __builtin_nontemporal_store(v, &o4[idx]);
    }
    return;
  }

  // ---- enum-only blocks ----
  if (t == 0) { posA[g] = 0; posI[g] = 0; }

  const float gx0 = gt_boxes[g * 4 + 0], gy0 = gt_boxes[g * 4 + 1];
  const float gx1 = gt_boxes[g * 4 + 2], gy1 = gt_boxes[g * 4 + 3];
  const int cls = gt_labels[g];
  const bool valid = (gt_mask[g] != 0);
  const float ga1 = (gx1 - gx0) * (gy1 - gy0);

  unsigned long long tkkey[TOPKN];
#pragma unroll
  for (int k = 0; k < TOPKN; k++) tkkey[k] = 0ull;

  if (valid) {
    const int strides[3] = {8, 16, 32};
    const int grids[3] = {80, 40, 20};
    const int offs[3] = {0, 6400, 8000};
    for (int lvl = 0; lvl < 3; lvl++) {
      const float s = (float)strides[lvl];
      const int n = grids[lvl], off = offs[lvl];
      int lx = max(0, (int)floorf(gx0 / s - 0.5f) - 1);
      int hx = min(n - 1, (int)ceilf(gx1 / s - 0.5f) + 1);
      int ly = max(0, (int)floorf(gy0 / s - 0.5f) - 1);
      int hy = min(n - 1, (int)ceilf(gy1 / s - 0.5f) + 1);
      if (hx < lx || hy < ly) continue;
      const int w = hx - lx + 1;
      const int m = w * (hy - ly + 1);
      for (int i = t; i < m; i += 256) {
        const int ix = lx + i % w;
        const int iy = ly + i / w;
        const float apx = ((float)ix + 0.5f) * s;
        const float apy = ((float)iy + 0.5f) * s;
        const float d = fminf(fminf(apx - gx0, apy - gy0),
                              fminf(gx1 - apx, gy1 - apy));
        if (!(d > 1e-8f)) continue;
        const int a = off + iy * n + ix;
        const float* pb = pred_boxes + ((size_t)b * AA + a) * 4;
        const float p0 = pb[0], p1 = pb[1], p2 = pb[2], p3 = pb[3];
        const float iw = fmaxf(fminf(gx1, p2) - fmaxf(gx0, p0), 0.0f);
        const float ih = fmaxf(fminf(gy1, p3) - fmaxf(gy0, p1), 0.0f);
        const float inter = iw * ih;
        const float a2 = (p2 - p0) * (p3 - p1);
        const float iou = fmaxf(inter / (ga1 + a2 - inter + 1e-10f), 0.0f);
        const float sc = pred_scores[((size_t)b * AA + a) * CC + cls];
        const float i2 = iou * iou;
        const float align_v = sc * i2 * i2 * i2;
        const unsigned long long key =
            ((unsigned long long)__float_as_uint(align_v) << 32) |
            (unsigned int)(AA - a);
        if (key > tkkey[TOPKN - 1]) {
          tkkey[TOPKN - 1] = key;
#pragma unroll
          for (int k = TOPKN - 1; k > 0; k--) {
            if (tkkey[k] > tkkey[k - 1]) {
              unsigned long long tmp = tkkey[k];
              tkkey[k] = tkkey[k - 1];
              tkkey[k - 1] = tmp;
            }
          }
        }
      }
    }
  }

  __shared__ unsigned long long s_key[256][TOPKN + 1];  // stride 88B: free
#pragma unroll
  for (int k = 0; k < TOPKN; k++) s_key[t][k] = tkkey[k];
  __syncthreads();

  for (int stride = 128; stride >= 1; stride >>= 1) {
    if (t < stride) {
      unsigned long long mk[TOPKN];
      int p = 0, q = 0;
#pragma unroll
      for (int k = 0; k < TOPKN; k++) {
        const unsigned long long k1 = s_key[t][p], k2 = s_key[t + stride][q];
        if (k1 >= k2) { mk[k] = k1; p++; } else { mk[k] = k2; q++; }
      }
#pragma unroll
      for (int k = 0; k < TOPKN; k++) s_key[t][k] = mk[k];
    }
    __syncthreads();
  }

  if (t < TOPKN) {
    const unsigned long long key = s_key[0][t];
    tk[g * TOPKN + t] = (key != 0ull) ? (AA - (int)(key & 0xffffffffu)) : -1;
  }
}

// ===========================================================================
// K2: grid (NBB, BB) x 64t (validated). Block (j,b) resolves ONLY gt row
// j's 10 candidates against the batch's 320-entry LDS list (wave-uniform
// scan = broadcast). cnt==1 -> row j; cnt>1 -> first-max argmax_j over all
// 32 gts. Compact results (resj/resAl); atomicMax pos.
// ===========================================================================
__global__ __launch_bounds__(64) void assign_sparse_kernel(
    const float* __restrict__ pred_scores, const float* __restrict__ pred_boxes,
    const float* __restrict__ anchor_points, const int* __restrict__ gt_labels,
    const float* __restrict__ gt_boxes, const int* __restrict__ gt_mask,
    const int* __restrict__ tk,
    int* __restrict__ resj, float* __restrict__ resAl,
    int* __restrict__ posA, int* __restrict__ posI) {
  const int j = blockIdx.x, b = blockIdx.y, t = threadIdx.x;

  __shared__ float sbox[NBB][4];
  __shared__ int scls[NBB];
  __shared__ int svalid[NBB];
  __shared__ int sa[NBB * TOPKN];

  if (t < NBB) {
    const int g = b * NBB + t;
    sbox[t][0] = gt_boxes[g * 4 + 0];
    sbox[t][1] = gt_boxes[g * 4 + 1];
    sbox[t][2] = gt_boxes[g * 4 + 2];
    sbox[t][3] = gt_boxes[g * 4 + 3];
    scls[t] = gt_labels[g];
    svalid[t] = (gt_mask[g] != 0) ? 1 : 0;
  }
  for (int e = t; e < NBB * TOPKN; e += 64) sa[e] = tk[b * NBB * TOPKN + e];
  __syncthreads();

  if (t >= TOPKN) return;  // no barriers below
  const int a = sa[j * TOPKN + t];
  if (a < 0) return;

  int cnt = 0;
  for (int q = 0; q < NBB * TOPKN; q++) cnt += (sa[q] == a) ? 1 : 0;

  const float apx = anchor_points[a * 2 + 0];
  const float apy = anchor_points[a * 2 + 1];
  const float* pb = pred_boxes + ((size_t)b * AA + a) * 4;
  const float p0 = pb[0], p1 = pb[1], p2 = pb[2], p3 = pb[3];
  const float a2 = (p2 - p0) * (p3 - p1);

  int jj;
  float iou_f;
  if (cnt == 1) {
    jj = j;
    const float gx0 = sbox[j][0], gy0 = sbox[j][1];
    const float gx1 = sbox[j][2], gy1 = sbox[j][3];
    const float iw = fmaxf(fminf(gx1, p2) - fmaxf(gx0, p0), 0.0f);
    const float ih = fmaxf(fminf(gy1, p3) - fmaxf(gy0, p1), 0.0f);
    const float inter = iw * ih;
    const float a1 = (gx1 - gx0) * (gy1 - gy0);
    iou_f = fmaxf(inter / (a1 + a2 - inter + 1e-10f), 0.0f);
  } else {
    float best_iou = -1.0f;
    int best_j = 0;
    for (int jq = 0; jq < NBB; jq++) {
      const float gx0 = sbox[jq][0], gy0 = sbox[jq][1];
      const float gx1 = sbox[jq][2], gy1 = sbox[jq][3];
      const float d = fminf(fminf(apx - gx0, apy - gy0),
                            fminf(gx1 - apx, gy1 - apy));
      float iou = 0.0f;
      if (svalid[jq] && d > 1e-8f) {
        const float iw = fmaxf(fminf(gx1, p2) - fmaxf(gx0, p0), 0.0f);
        const float ih = fmaxf(fminf(gy1, p3) - fmaxf(gy0, p1), 0.0f);
        const float inter = iw * ih;
        const float a1 = (gx1 - gx0) * (gy1 - gy0);
        iou = fmaxf(inter / (a1 + a2 - inter + 1e-10f), 0.0f);
      }
      if (iou > best_iou) { best_iou = iou; best_j = jq; }  // first-max
    }
    jj = best_j;
    iou_f = best_iou;
  }

  const float sc = pred_scores[((size_t)b * AA + a) * CC + scls[jj]];
  const float i2 = iou_f * iou_f;
  const float align_v = sc * i2 * i2 * i2;
  const int e = (b * NBB + j) * TOPKN + t;
  resj[e] = jj;
  resAl[e] = align_v;
  atomicMax(&posA[b * NBB + jj], __float_as_int(align_v));
  atomicMax(&posI[b * NBB + jj], __float_as_int(iou_f));
}

// ===========================================================================
// K3b: sparse scatter of assigned-anchor outputs over the defaults
// (validated). One thread per candidate entry (10240); duplicates
// value-identical.
// ===========================================================================
__global__ __launch_bounds__(256) void scatter_out_kernel(
    const int* __restrict__ gt_labels, const float* __restrict__ gt_boxes,
    const int* __restrict__ tk, const int* __restrict__ resj,
    const float* __restrict__ resAl, const int* __restrict__ posA,
    const int* __restrict__ posI, float* __restrict__ out) {
  const int e = blockIdx.x * 256 + threadIdx.x;
  if (e >= BB * NBB * TOPKN) return;
  const int a = tk[e];
  if (a < 0) return;
  const int b = e / (NBB * TOPKN);
  const int jj = resj[e];
  const float align_v = resAl[e];
  const float pa = __int_as_float(posA[b * NBB + jj]);
  const float pi = __int_as_float(posI[b * NBB + jj]);
  const float norm = align_v * pi / (pa + 1e-8f);
  int label = gt_labels[b * NBB + jj];
  label = min(max(label, 0), 80);
  const size_t aidx = (size_t)b * AA + a;

  out[aidx] = (float)label;                                       // labels
  *reinterpret_cast<float4*>(out + (size_t)BB * AA + aidx * 4) =  // boxes
      *reinterpret_cast<const float4*>(gt_boxes + ((size_t)b * NBB + jj) * 4);
  if (label < CC)
    out[(size_t)BB * AA * 5 + aidx * CC + label] = norm;          // scores
  out[(size_t)BB * AA * 85 + aidx] = 1.0f;                        // fg
}

// ===========================================================================
extern "C" void kernel_launch(void* const* d_in, const int* in_sizes, int n_in,
                              void* d_out, int out_size, void* d_ws, size_t ws_size,
                              hipStream_t stream) {
  const float* pred_scores = (const float*)d_in[0];
  const float* pred_boxes = (const float*)d_in[1];
  const float* anchor_points = (const float*)d_in[2];
  const int* gt_labels = (const int*)d_in[3];
  const float* gt_boxes = (const float*)d_in[4];
  const int* gt_mask = (const int*)d_in[5];
  float* out = (float*)d_out;
  char* ws = (char*)d_ws;

  // workspace: tk | posA | posI | resj | resAl (all small)
  const size_t off_tk = 0;                                  // 40 KB
  const size_t off_posA = off_tk + (size_t)BB * NBB * TOPKN * 4;
  const size_t off_posI = off_posA + 4096;
  const size_t off_resj = off_posI + 4096;                  // 40 KB
  const size_t off_resAl = off_resj + (size_t)BB * NBB * TOPKN * 4;

  int* tk = (int*)(ws + off_tk);
  int* posA = (int*)(ws + off_posA);
  int* posI = (int*)(ws + off_posI);
  int* resj = (int*)(ws + off_resj);
  float* resAl = (float*)(ws + off_resAl);

  dim3 g1(NBB, BB, 2);  // z=0: enum blocks, z=1: fill blocks
  gt_topk_kernel<<<g1, 256, 0, stream>>>(pred_scores, pred_boxes, gt_labels,
                                         gt_boxes, gt_mask, tk, posA, posI,
                                         out);

  dim3 g2(NBB, BB);
  assign_sparse_kernel<<<g2, 64, 0, stream>>>(
      pred_scores, pred_boxes, anchor_points, gt_labels, gt_boxes, gt_mask,
      tk, resj, resAl, posA, posI);

  const int ncand = BB * NBB * TOPKN;
  scatter_out_kernel<<<(ncand + 255) / 256, 256, 0, stream>>>(
      gt_labels, gt_boxes, tk, resj, resAl, posA, posI, out);
}